// Round 5
// baseline (271.383 us; speedup 1.0000x reference)
//
#include <hip/hip_runtime.h>
#include <hip/hip_bf16.h>
#include <string.h>

// Problem constants (B=8, S=4096, H=768, L=256, ATT_HID=1024)
#define M_TOK 32768   // B*S
#define H_DIM 768
#define AH    1024
#define NSEG  2048    // B*L
#define CAP   96      // max tokens per segment bucket (mean 16, max ~40 observed)

typedef __attribute__((ext_vector_type(8))) __bf16 bf16x8;
typedef __attribute__((ext_vector_type(4))) float f32x4;

// Fast tanh: 1 - 2/(exp(2x)+1). Saturates correctly; ~1e-5 rel err.
__device__ __forceinline__ float tanh_fast(float x) {
  float e = __expf(2.0f * x);
  return 1.0f - 2.0f * __builtin_amdgcn_rcpf(e + 1.0f);
}

// ---------------------------------------------------------------------------
// K0: prep = (blocks 0..767) transpose+convert W1 fp32 [768,1024] -> W1t bf16
// [1024,768]; (blocks 768..895) bucketed scatter of token ids by segment.
__global__ __launch_bounds__(256) void prep_kernel(
    const float* __restrict__ W1, __hip_bfloat16* __restrict__ W1t,
    const int* __restrict__ line_ids, int* __restrict__ cursor,
    int* __restrict__ order) {
  __shared__ float tile[32][33];
  if (blockIdx.x < 768) {
    int nt = blockIdx.x & 31, ktile = blockIdx.x >> 5;
    int n0 = nt * 32, k0 = ktile * 32;
    int tx = threadIdx.x & 31, ty = threadIdx.x >> 5;  // ty 0..7
    for (int r = ty; r < 32; r += 8)
      tile[r][tx] = W1[(size_t)(k0 + r) * AH + n0 + tx];
    __syncthreads();
    for (int r = ty; r < 32; r += 8)
      W1t[(size_t)(n0 + r) * H_DIM + k0 + tx] = __float2bfloat16(tile[tx][r]);
  } else {
    int t = (blockIdx.x - 768) * 256 + threadIdx.x;  // 128 blocks cover M_TOK
    int lid = line_ids[t];
    if (lid >= 0) {
      int seg = (t >> 12) * 256 + lid;
      int pos = atomicAdd(&cursor[seg], 1);
      if (pos < CAP) order[seg * CAP + pos] = t;
    }
  }
}

// ---------------------------------------------------------------------------
// K1: fused scores = tanh(bf16(X) @ W1t^T + b1) . W2, atomic per-row accum.
// 128x128 MFMA tile, BK=32. A staged from fp32 X with in-register cvt ->
// ds_write_b128 (kills the separate convert kernel); B staged via
// global_load_lds width-16 DMA. XCD swizzle: all 8 n-tiles of one m-tile run
// consecutively on one XCD so the A-tile stays in that XCD's L2.
__global__ __launch_bounds__(256) void attn_score_kernel(
    const float* __restrict__ Xf, const __hip_bfloat16* __restrict__ W1tg,
    const float* __restrict__ b1g, const float* __restrict__ W2g,
    float* __restrict__ scores) {
  __shared__ __align__(16) __bf16 As[128 * 32];
  __shared__ __align__(16) __bf16 Bs[128 * 32];

  const int tid = threadIdx.x;
  const int bid = blockIdx.x;
  const int xcd = bid & 7;                      // lands on XCD bid%8
  const int s   = bid >> 3;                     // 0..255 sequence on that XCD
  const int m0  = (xcd * 32 + (s >> 3)) * 128;  // 32 m-tiles per XCD
  const int n0  = (s & 7) * 128;                // 8 n-tiles, consecutive
  const int lane = tid & 63;
  const int wave = tid >> 6;
  const int wm   = (wave >> 1) * 64;
  const int wn   = (wave & 1) * 64;
  const int q8   = (lane >> 4) * 8;
  const int ml   = lane & 15;

  const __bf16* W = (const __bf16*)W1tg;

  const int rowoff = tid >> 2;         // 0..63
  const int colk   = (tid & 3) * 8;    // 0,8,16,24

  f32x4 acc[4][4];
#pragma unroll
  for (int i = 0; i < 4; i++)
#pragma unroll
    for (int j = 0; j < 4; j++) acc[i][j] = (f32x4)0.f;

  for (int kt = 0; kt < H_DIM; kt += 32) {
#pragma unroll
    for (int r = 0; r < 2; ++r) {
      // B tile: bf16 DMA direct to LDS
      const __bf16* gb = W + (size_t)(n0 + r * 64 + rowoff) * H_DIM + kt + colk;
      __builtin_amdgcn_global_load_lds(
          (const __attribute__((address_space(1))) void*)gb,
          (__attribute__((address_space(3))) void*)&Bs[(r * 256 + tid) * 8],
          16, 0, 0);
      // A tile: fp32 load + cvt + ds_write_b128
      const float* ga = Xf + (size_t)(m0 + r * 64 + rowoff) * H_DIM + kt + colk;
      float4 v0 = *(const float4*)ga;
      float4 v1 = *(const float4*)(ga + 4);
      __hip_bfloat16 h[8] = {
          __float2bfloat16(v0.x), __float2bfloat16(v0.y),
          __float2bfloat16(v0.z), __float2bfloat16(v0.w),
          __float2bfloat16(v1.x), __float2bfloat16(v1.y),
          __float2bfloat16(v1.z), __float2bfloat16(v1.w)};
      memcpy(&As[(r * 256 + tid) * 8], h, 16);
    }
    __syncthreads();

    bf16x8 af[4], bf[4];
#pragma unroll
    for (int i = 0; i < 4; i++)
      af[i] = *(const bf16x8*)&As[(wm + i * 16 + ml) * 32 + q8];
#pragma unroll
    for (int j = 0; j < 4; j++)
      bf[j] = *(const bf16x8*)&Bs[(wn + j * 16 + ml) * 32 + q8];

#pragma unroll
    for (int i = 0; i < 4; i++)
#pragma unroll
      for (int j = 0; j < 4; j++)
        acc[i][j] = __builtin_amdgcn_mfma_f32_16x16x32_bf16(af[i], bf[j],
                                                            acc[i][j], 0, 0, 0);
    __syncthreads();
  }

  // Epilogue: per-row partial of tanh(C + b1) . W2 ; b2 cancels in softmax.
  float b1v[4], w2v[4];
#pragma unroll
  for (int j = 0; j < 4; j++) {
    int n = n0 + wn + j * 16 + ml;
    b1v[j] = b1g[n];
    w2v[j] = W2g[n];
  }
  const int q4 = (lane >> 4) * 4;
#pragma unroll
  for (int i = 0; i < 4; i++) {
#pragma unroll
    for (int p = 0; p < 4; p++) {
      float t = 0.f;
#pragma unroll
      for (int j = 0; j < 4; j++)
        t += tanh_fast(acc[i][j][p] + b1v[j]) * w2v[j];
      t += __shfl_xor(t, 1);
      t += __shfl_xor(t, 2);
      t += __shfl_xor(t, 4);
      t += __shfl_xor(t, 8);
      if (ml == 0) atomicAdd(&scores[m0 + wm + i * 16 + q4 + p], t);
    }
  }
}

// ---------------------------------------------------------------------------
// K2: per-segment softmax + float4 weighted sum, 4-deep pipelined gather.
__global__ __launch_bounds__(256) void aggregate_kernel(
    const float4* __restrict__ X4, const float* __restrict__ scores,
    const int* __restrict__ cursor, const int* __restrict__ order,
    float4* __restrict__ out4, float* __restrict__ out_mask) {
  __shared__ float sw[CAP];
  __shared__ int   sidx[CAP];
  __shared__ float wred[4];
  const int seg = blockIdx.x;
  const int tid = threadIdx.x;
  int cnt = cursor[seg];
  if (cnt > CAP) cnt = CAP;
  if (tid == 0) out_mask[seg] = cnt > 0 ? 1.f : 0.f;
  if (cnt == 0) {
    if (tid < H_DIM / 4)
      out4[(size_t)seg * (H_DIM / 4) + tid] = make_float4(0.f, 0.f, 0.f, 0.f);
    return;
  }
  const int lane = tid & 63, wave = tid >> 6;
  float lmax = -3.4e38f;
  if (tid < cnt) {
    int idx = order[seg * CAP + tid];
    sidx[tid] = idx;
    float sc = scores[idx];
    sw[tid] = sc;
    lmax = sc;
  }
#pragma unroll
  for (int d = 1; d < 64; d <<= 1) lmax = fmaxf(lmax, __shfl_xor(lmax, d));
  if (lane == 0) wred[wave] = lmax;
  __syncthreads();
  float m = fmaxf(fmaxf(wred[0], wred[1]), fmaxf(wred[2], wred[3]));
  float lsum = 0.f;
  if (tid < cnt) {
    float e = __expf(sw[tid] - m);
    sw[tid] = e;
    lsum = e;
  }
#pragma unroll
  for (int d = 1; d < 64; d <<= 1) lsum += __shfl_xor(lsum, d);
  __syncthreads();                 // wred(max) consumed before overwrite
  if (lane == 0) wred[wave] = lsum;
  __syncthreads();
  float denom = wred[0] + wred[1] + wred[2] + wred[3];
  float inv = __builtin_amdgcn_rcpf(fmaxf(denom, 1e-20f));
  if (tid < cnt) sw[tid] *= inv;
  __syncthreads();
  if (tid < H_DIM / 4) {           // 192 lanes, 16B each, coalesced per row
    const float4* base = X4 + tid;
    float4 acc = make_float4(0.f, 0.f, 0.f, 0.f);
    int t = 0;
    for (; t + 4 <= cnt; t += 4) { // 4 independent loads in flight
      int i0 = sidx[t], i1 = sidx[t + 1], i2 = sidx[t + 2], i3 = sidx[t + 3];
      float4 v0 = base[(size_t)i0 * (H_DIM / 4)];
      float4 v1 = base[(size_t)i1 * (H_DIM / 4)];
      float4 v2 = base[(size_t)i2 * (H_DIM / 4)];
      float4 v3 = base[(size_t)i3 * (H_DIM / 4)];
      float w0 = sw[t], w1 = sw[t + 1], w2 = sw[t + 2], w3 = sw[t + 3];
      acc.x += w0 * v0.x + w1 * v1.x + w2 * v2.x + w3 * v3.x;
      acc.y += w0 * v0.y + w1 * v1.y + w2 * v2.y + w3 * v3.y;
      acc.z += w0 * v0.z + w1 * v1.z + w2 * v2.z + w3 * v3.z;
      acc.w += w0 * v0.w + w1 * v1.w + w2 * v2.w + w3 * v3.w;
    }
    for (; t < cnt; ++t) {
      float w = sw[t];
      float4 v = base[(size_t)sidx[t] * (H_DIM / 4)];
      acc.x += w * v.x; acc.y += w * v.y; acc.z += w * v.z; acc.w += w * v.w;
    }
    out4[(size_t)seg * (H_DIM / 4) + tid] = acc;
  }
}

// ---------------------------------------------------------------------------
extern "C" void kernel_launch(void* const* d_in, const int* in_sizes, int n_in,
                              void* d_out, int out_size, void* d_ws, size_t ws_size,
                              hipStream_t stream) {
  const float* X        = (const float*)d_in[0];
  const int*   line_ids = (const int*)d_in[1];
  const float* W1       = (const float*)d_in[2];
  const float* b1       = (const float*)d_in[3];
  const float* W2       = (const float*)d_in[4];
  // d_in[5] = b2: constant shift, cancels in softmax -> unused.

  char* p = (char*)d_ws;
  __hip_bfloat16* W1t = (__hip_bfloat16*)p;  p += 1572864;
  float* scores  = (float*)p;                p += 131072;
  int*   cursor  = (int*)p;                  p += 8192;
  int*   order   = (int*)p;                  p += (size_t)NSEG * CAP * 4;

  float* out_feats = (float*)d_out;
  float* out_mask  = out_feats + (size_t)NSEG * H_DIM;

  // zero scores + cursor (contiguous region)
  hipMemsetAsync(scores, 0, 131072 + 8192, stream);

  prep_kernel<<<768 + M_TOK / 256, 256, 0, stream>>>(W1, W1t, line_ids,
                                                     cursor, order);
  attn_score_kernel<<<2048, 256, 0, stream>>>(X, W1t, b1, W2, scores);
  aggregate_kernel<<<NSEG, 256, 0, stream>>>((const float4*)X, scores, cursor,
                                             order, (float4*)out_feats, out_mask);
}

// Round 6
// 252.883 us; speedup vs baseline: 1.0732x; 1.0732x over previous
//
#include <hip/hip_runtime.h>
#include <hip/hip_bf16.h>
#include <string.h>

// Problem constants (B=8, S=4096, H=768, L=256, ATT_HID=1024)
#define M_TOK 32768   // B*S
#define H_DIM 768
#define AH    1024
#define NSEG  2048    // B*L
#define CAP   96      // max tokens per segment bucket (mean 16)
#define CONV_BLOCKS 12288  // M_TOK*H_DIM / 8 elems-per-thread / 256 threads

typedef __attribute__((ext_vector_type(8))) __bf16 bf16x8;
typedef __attribute__((ext_vector_type(4))) float f32x4;

// Fast tanh: 1 - 2/(exp(2x)+1). Saturates correctly; ~1e-5 rel err.
__device__ __forceinline__ float tanh_fast(float x) {
  float e = __expf(2.0f * x);
  return 1.0f - 2.0f * __builtin_amdgcn_rcpf(e + 1.0f);
}

__device__ __forceinline__ float bf2f(unsigned short u) {
  unsigned int v = (unsigned int)u << 16;
  float f;
  memcpy(&f, &v, 4);
  return f;
}

// ---------------------------------------------------------------------------
// K0: prep, three block ranges:
//   [0,768)            : transpose+convert W1 fp32 [768,1024] -> W1t bf16 [1024,768]
//   [768,896)          : bucketed scatter of token ids by segment
//   [896,896+12288)    : convert X fp32 -> Xb bf16, 8 elems/thread
__global__ __launch_bounds__(256) void prep_kernel(
    const float* __restrict__ W1, __hip_bfloat16* __restrict__ W1t,
    const int* __restrict__ line_ids, int* __restrict__ cursor,
    int* __restrict__ order, const float4* __restrict__ X4,
    uint4* __restrict__ Xb4) {
  __shared__ float tile[32][33];
  if (blockIdx.x < 768) {
    int nt = blockIdx.x & 31, ktile = blockIdx.x >> 5;
    int n0 = nt * 32, k0 = ktile * 32;
    int tx = threadIdx.x & 31, ty = threadIdx.x >> 5;  // ty 0..7
    for (int r = ty; r < 32; r += 8)
      tile[r][tx] = W1[(size_t)(k0 + r) * AH + n0 + tx];
    __syncthreads();
    for (int r = ty; r < 32; r += 8)
      W1t[(size_t)(n0 + r) * H_DIM + k0 + tx] = __float2bfloat16(tile[tx][r]);
  } else if (blockIdx.x < 896) {
    int t = (blockIdx.x - 768) * 256 + threadIdx.x;  // 128 blocks cover M_TOK
    int lid = line_ids[t];
    if (lid >= 0) {
      int seg = (t >> 12) * 256 + lid;
      int pos = atomicAdd(&cursor[seg], 1);
      if (pos < CAP) order[seg * CAP + pos] = t;
    }
  } else {
    int i = (blockIdx.x - 896) * 256 + threadIdx.x;  // 8 elems per thread
    float4 v0 = X4[i * 2];
    float4 v1 = X4[i * 2 + 1];
    __hip_bfloat16 h[8] = {
        __float2bfloat16(v0.x), __float2bfloat16(v0.y),
        __float2bfloat16(v0.z), __float2bfloat16(v0.w),
        __float2bfloat16(v1.x), __float2bfloat16(v1.y),
        __float2bfloat16(v1.z), __float2bfloat16(v1.w)};
    uint4 p;
    memcpy(&p, h, 16);
    Xb4[i] = p;
  }
}

// ---------------------------------------------------------------------------
// K1: fused scores = tanh(Xb @ W1t^T + b1) . W2, atomic per-row accumulate.
// 128x128 MFMA tile, BK=32, global_load_lds width-16 staging (R4-proven).
// XCD swizzle: all 8 n-tiles of one m-tile run consecutively on one XCD.
__global__ __launch_bounds__(256) void attn_score_kernel(
    const __hip_bfloat16* __restrict__ Xbg,
    const __hip_bfloat16* __restrict__ W1tg, const float* __restrict__ b1g,
    const float* __restrict__ W2g, float* __restrict__ scores) {
  __shared__ __align__(16) __bf16 As[128 * 32];
  __shared__ __align__(16) __bf16 Bs[128 * 32];

  const int tid = threadIdx.x;
  const int bid = blockIdx.x;
  const int xcd = bid & 7;                      // lands on XCD bid%8
  const int s   = bid >> 3;                     // 0..255 sequence on that XCD
  const int m0  = (xcd * 32 + (s >> 3)) * 128;  // 32 m-tiles per XCD
  const int n0  = (s & 7) * 128;                // 8 n-tiles, consecutive
  const int lane = tid & 63;
  const int wave = tid >> 6;
  const int wm   = (wave >> 1) * 64;
  const int wn   = (wave & 1) * 64;
  const int q8   = (lane >> 4) * 8;
  const int ml   = lane & 15;

  const __bf16* Xb = (const __bf16*)Xbg;
  const __bf16* W  = (const __bf16*)W1tg;

  const int rowoff = tid >> 2;         // 0..63
  const int colk   = (tid & 3) * 8;    // 0,8,16,24

  f32x4 acc[4][4];
#pragma unroll
  for (int i = 0; i < 4; i++)
#pragma unroll
    for (int j = 0; j < 4; j++) acc[i][j] = (f32x4)0.f;

  for (int kt = 0; kt < H_DIM; kt += 32) {
#pragma unroll
    for (int r = 0; r < 2; ++r) {
      const __bf16* ga = Xb + (size_t)(m0 + r * 64 + rowoff) * H_DIM + kt + colk;
      __builtin_amdgcn_global_load_lds(
          (const __attribute__((address_space(1))) void*)ga,
          (__attribute__((address_space(3))) void*)&As[(r * 256 + tid) * 8],
          16, 0, 0);
      const __bf16* gb = W + (size_t)(n0 + r * 64 + rowoff) * H_DIM + kt + colk;
      __builtin_amdgcn_global_load_lds(
          (const __attribute__((address_space(1))) void*)gb,
          (__attribute__((address_space(3))) void*)&Bs[(r * 256 + tid) * 8],
          16, 0, 0);
    }
    __syncthreads();

    bf16x8 af[4], bf[4];
#pragma unroll
    for (int i = 0; i < 4; i++)
      af[i] = *(const bf16x8*)&As[(wm + i * 16 + ml) * 32 + q8];
#pragma unroll
    for (int j = 0; j < 4; j++)
      bf[j] = *(const bf16x8*)&Bs[(wn + j * 16 + ml) * 32 + q8];

#pragma unroll
    for (int i = 0; i < 4; i++)
#pragma unroll
      for (int j = 0; j < 4; j++)
        acc[i][j] = __builtin_amdgcn_mfma_f32_16x16x32_bf16(af[i], bf[j],
                                                            acc[i][j], 0, 0, 0);
    __syncthreads();
  }

  // Epilogue: per-row partial of tanh(C + b1) . W2 ; b2 cancels in softmax.
  float b1v[4], w2v[4];
#pragma unroll
  for (int j = 0; j < 4; j++) {
    int n = n0 + wn + j * 16 + ml;
    b1v[j] = b1g[n];
    w2v[j] = W2g[n];
  }
  const int q4 = (lane >> 4) * 4;
#pragma unroll
  for (int i = 0; i < 4; i++) {
#pragma unroll
    for (int p = 0; p < 4; p++) {
      float t = 0.f;
#pragma unroll
      for (int j = 0; j < 4; j++)
        t += tanh_fast(acc[i][j][p] + b1v[j]) * w2v[j];
      t += __shfl_xor(t, 1);
      t += __shfl_xor(t, 2);
      t += __shfl_xor(t, 4);
      t += __shfl_xor(t, 8);
      if (ml == 0) atomicAdd(&scores[m0 + wm + i * 16 + q4 + p], t);
    }
  }
}

// ---------------------------------------------------------------------------
// K2: per-segment softmax + weighted sum gathered from bf16 Xb (LLC-hot,
// half the bytes of fp32). Weights convex -> bf16 X rounding adds <2e-3.
// 192 threads x ushort4 (8B) covers a 768-elem row; 4-deep pipelined gather.
__global__ __launch_bounds__(256) void aggregate_kernel(
    const ushort* __restrict__ Xb, const float* __restrict__ scores,
    const int* __restrict__ cursor, const int* __restrict__ order,
    float4* __restrict__ out4, float* __restrict__ out_mask) {
  __shared__ float sw[CAP];
  __shared__ int   sidx[CAP];
  __shared__ float wred[4];
  const int seg = blockIdx.x;
  const int tid = threadIdx.x;
  int cnt = cursor[seg];
  if (cnt > CAP) cnt = CAP;
  if (tid == 0) out_mask[seg] = cnt > 0 ? 1.f : 0.f;
  if (cnt == 0) {
    if (tid < H_DIM / 4)
      out4[(size_t)seg * (H_DIM / 4) + tid] = make_float4(0.f, 0.f, 0.f, 0.f);
    return;
  }
  const int lane = tid & 63, wave = tid >> 6;
  float lmax = -3.4e38f;
  if (tid < cnt) {
    int idx = order[seg * CAP + tid];
    sidx[tid] = idx;
    float sc = scores[idx];
    sw[tid] = sc;
    lmax = sc;
  }
#pragma unroll
  for (int d = 1; d < 64; d <<= 1) lmax = fmaxf(lmax, __shfl_xor(lmax, d));
  if (lane == 0) wred[wave] = lmax;
  __syncthreads();
  float m = fmaxf(fmaxf(wred[0], wred[1]), fmaxf(wred[2], wred[3]));
  float lsum = 0.f;
  if (tid < cnt) {
    float e = __expf(sw[tid] - m);
    sw[tid] = e;
    lsum = e;
  }
#pragma unroll
  for (int d = 1; d < 64; d <<= 1) lsum += __shfl_xor(lsum, d);
  __syncthreads();                 // wred(max) consumed before overwrite
  if (lane == 0) wred[wave] = lsum;
  __syncthreads();
  float denom = wred[0] + wred[1] + wred[2] + wred[3];
  float inv = __builtin_amdgcn_rcpf(fmaxf(denom, 1e-20f));
  if (tid < cnt) sw[tid] *= inv;
  __syncthreads();
  if (tid < H_DIM / 4) {           // 192 lanes, 8B each
    const ushort4* base = (const ushort4*)Xb + tid;  // elem offset = tid*4
    float4 acc = make_float4(0.f, 0.f, 0.f, 0.f);
    int t = 0;
    for (; t + 4 <= cnt; t += 4) { // 4 independent loads in flight
      ushort4 u0 = base[(size_t)sidx[t]     * (H_DIM / 4)];
      ushort4 u1 = base[(size_t)sidx[t + 1] * (H_DIM / 4)];
      ushort4 u2 = base[(size_t)sidx[t + 2] * (H_DIM / 4)];
      ushort4 u3 = base[(size_t)sidx[t + 3] * (H_DIM / 4)];
      float w0 = sw[t], w1 = sw[t + 1], w2 = sw[t + 2], w3 = sw[t + 3];
      acc.x += w0 * bf2f(u0.x) + w1 * bf2f(u1.x) + w2 * bf2f(u2.x) + w3 * bf2f(u3.x);
      acc.y += w0 * bf2f(u0.y) + w1 * bf2f(u1.y) + w2 * bf2f(u2.y) + w3 * bf2f(u3.y);
      acc.z += w0 * bf2f(u0.z) + w1 * bf2f(u1.z) + w2 * bf2f(u2.z) + w3 * bf2f(u3.z);
      acc.w += w0 * bf2f(u0.w) + w1 * bf2f(u1.w) + w2 * bf2f(u2.w) + w3 * bf2f(u3.w);
    }
    for (; t < cnt; ++t) {
      ushort4 u = base[(size_t)sidx[t] * (H_DIM / 4)];
      float w = sw[t];
      acc.x += w * bf2f(u.x); acc.y += w * bf2f(u.y);
      acc.z += w * bf2f(u.z); acc.w += w * bf2f(u.w);
    }
    out4[(size_t)seg * (H_DIM / 4) + tid] = acc;
  }
}

// ---------------------------------------------------------------------------
extern "C" void kernel_launch(void* const* d_in, const int* in_sizes, int n_in,
                              void* d_out, int out_size, void* d_ws, size_t ws_size,
                              hipStream_t stream) {
  const float* X        = (const float*)d_in[0];
  const int*   line_ids = (const int*)d_in[1];
  const float* W1       = (const float*)d_in[2];
  const float* b1       = (const float*)d_in[3];
  const float* W2       = (const float*)d_in[4];
  // d_in[5] = b2: constant shift, cancels in softmax -> unused.

  char* p = (char*)d_ws;
  __hip_bfloat16* Xb  = (__hip_bfloat16*)p;  p += (size_t)M_TOK * H_DIM * 2;
  __hip_bfloat16* W1t = (__hip_bfloat16*)p;  p += 1572864;
  float* scores  = (float*)p;                p += 131072;
  int*   cursor  = (int*)p;                  p += 8192;
  int*   order   = (int*)p;                  p += (size_t)NSEG * CAP * 4;

  float* out_feats = (float*)d_out;
  float* out_mask  = out_feats + (size_t)NSEG * H_DIM;

  // zero scores + cursor (contiguous region)
  hipMemsetAsync(scores, 0, 131072 + 8192, stream);

  prep_kernel<<<896 + CONV_BLOCKS, 256, 0, stream>>>(
      W1, W1t, line_ids, cursor, order, (const float4*)X, (uint4*)Xb);
  attn_score_kernel<<<2048, 256, 0, stream>>>(Xb, W1t, b1, W2, scores);
  aggregate_kernel<<<NSEG, 256, 0, stream>>>((const ushort*)Xb, scores, cursor,
                                             order, (float4*)out_feats, out_mask);
}

// Round 7
// 252.178 us; speedup vs baseline: 1.0762x; 1.0028x over previous
//
#include <hip/hip_runtime.h>
#include <hip/hip_bf16.h>
#include <string.h>

// Problem constants (B=8, S=4096, H=768, L=256, ATT_HID=1024)
#define M_TOK 32768   // B*S
#define H_DIM 768
#define AH    1024
#define NSEG  2048    // B*L
#define CAP   96      // max tokens per segment bucket (mean 16)
#define CONV_BLOCKS 12288  // M_TOK*H_DIM / 8 elems-per-thread / 256 threads

typedef __attribute__((ext_vector_type(8))) __bf16 bf16x8;
typedef __attribute__((ext_vector_type(4))) float f32x4;

// Fast tanh: 1 - 2/(exp(2x)+1). Saturates correctly; ~1e-5 rel err.
__device__ __forceinline__ float tanh_fast(float x) {
  float e = __expf(2.0f * x);
  return 1.0f - 2.0f * __builtin_amdgcn_rcpf(e + 1.0f);
}

__device__ __forceinline__ float bf2f(unsigned short u) {
  unsigned int v = (unsigned int)u << 16;
  float f;
  memcpy(&f, &v, 4);
  return f;
}

// ---------------------------------------------------------------------------
// K0: prep, three block ranges:
//   [0,768)            : transpose+convert W1 fp32 [768,1024] -> W1t bf16 [1024,768]
//   [768,896)          : bucketed scatter of token ids by segment
//   [896,896+12288)    : convert X fp32 -> Xb bf16, 8 elems/thread
__global__ __launch_bounds__(256) void prep_kernel(
    const float* __restrict__ W1, __hip_bfloat16* __restrict__ W1t,
    const int* __restrict__ line_ids, int* __restrict__ cursor,
    int* __restrict__ order, const float4* __restrict__ X4,
    uint4* __restrict__ Xb4) {
  __shared__ float tile[32][33];
  if (blockIdx.x < 768) {
    int nt = blockIdx.x & 31, ktile = blockIdx.x >> 5;
    int n0 = nt * 32, k0 = ktile * 32;
    int tx = threadIdx.x & 31, ty = threadIdx.x >> 5;  // ty 0..7
    for (int r = ty; r < 32; r += 8)
      tile[r][tx] = W1[(size_t)(k0 + r) * AH + n0 + tx];
    __syncthreads();
    for (int r = ty; r < 32; r += 8)
      W1t[(size_t)(n0 + r) * H_DIM + k0 + tx] = __float2bfloat16(tile[tx][r]);
  } else if (blockIdx.x < 896) {
    int t = (blockIdx.x - 768) * 256 + threadIdx.x;  // 128 blocks cover M_TOK
    int lid = line_ids[t];
    if (lid >= 0) {
      int seg = (t >> 12) * 256 + lid;
      int pos = atomicAdd(&cursor[seg], 1);
      if (pos < CAP) order[seg * CAP + pos] = t;
    }
  } else {
    int i = (blockIdx.x - 896) * 256 + threadIdx.x;  // 8 elems per thread
    float4 v0 = X4[i * 2];
    float4 v1 = X4[i * 2 + 1];
    __hip_bfloat16 h[8] = {
        __float2bfloat16(v0.x), __float2bfloat16(v0.y),
        __float2bfloat16(v0.z), __float2bfloat16(v0.w),
        __float2bfloat16(v1.x), __float2bfloat16(v1.y),
        __float2bfloat16(v1.z), __float2bfloat16(v1.w)};
    uint4 p;
    memcpy(&p, h, 16);
    Xb4[i] = p;
  }
}

// ---------------------------------------------------------------------------
// K1: fused scores = tanh(Xb @ W1t^T + b1) . W2, atomic per-row accumulate.
// 128x128 MFMA tile, BK=64 (24 barriers instead of 48), global_load_lds
// width-16 staging, XCD swizzle (8 n-tiles of one m-tile stay on one XCD).
// XOR bank swizzle: logical granule g (16B) of row r stored at physical
// granule g^(r&7) -> ds_read_b128 spreads over all 8 bank groups (2-way
// aliasing = free) while global loads stay 128B-coalesced (granules only
// permuted within a row).
__global__ __launch_bounds__(256) void attn_score_kernel(
    const __hip_bfloat16* __restrict__ Xbg,
    const __hip_bfloat16* __restrict__ W1tg, const float* __restrict__ b1g,
    const float* __restrict__ W2g, float* __restrict__ scores) {
  __shared__ __align__(16) __bf16 As[128 * 64];   // 16 KB
  __shared__ __align__(16) __bf16 Bs[128 * 64];   // 16 KB

  const int tid = threadIdx.x;
  const int bid = blockIdx.x;
  const int xcd = bid & 7;                      // lands on XCD bid%8
  const int s   = bid >> 3;                     // 0..255 sequence on that XCD
  const int m0  = (xcd * 32 + (s >> 3)) * 128;  // 32 m-tiles per XCD
  const int n0  = (s & 7) * 128;                // 8 n-tiles, consecutive
  const int lane = tid & 63;
  const int wave = tid >> 6;
  const int wm   = (wave >> 1) * 64;
  const int wn   = (wave & 1) * 64;
  const int ml   = lane & 15;
  const int gsw  = lane & 7;                    // == row&7 for all fragment rows

  const __bf16* Xb = (const __bf16*)Xbg;
  const __bf16* W  = (const __bf16*)W1tg;

  // Staging: thread t covers row (p*32 + t>>3), swizzled granule (t&7)^(row&7).
  const int srow = tid >> 3;                       // 0..31
  const int scol = ((tid & 7) ^ (srow & 7)) * 8;   // swizzled source column

  f32x4 acc[4][4];
#pragma unroll
  for (int i = 0; i < 4; i++)
#pragma unroll
    for (int j = 0; j < 4; j++) acc[i][j] = (f32x4)0.f;

  for (int kt = 0; kt < H_DIM; kt += 64) {
#pragma unroll
    for (int p = 0; p < 4; ++p) {
      const __bf16* ga = Xb + (size_t)(m0 + p * 32 + srow) * H_DIM + kt + scol;
      __builtin_amdgcn_global_load_lds(
          (const __attribute__((address_space(1))) void*)ga,
          (__attribute__((address_space(3))) void*)&As[p * 2048 + tid * 8],
          16, 0, 0);
      const __bf16* gb = W + (size_t)(n0 + p * 32 + srow) * H_DIM + kt + scol;
      __builtin_amdgcn_global_load_lds(
          (const __attribute__((address_space(1))) void*)gb,
          (__attribute__((address_space(3))) void*)&Bs[p * 2048 + tid * 8],
          16, 0, 0);
    }
    __syncthreads();

#pragma unroll
    for (int c = 0; c < 2; ++c) {
      const int gq = c * 4 + (lane >> 4);          // logical granule 0..7
      const int gp = (gq ^ gsw) * 8;               // physical (swizzled)
      bf16x8 af[4], bf[4];
#pragma unroll
      for (int i = 0; i < 4; i++)
        af[i] = *(const bf16x8*)&As[(wm + i * 16 + ml) * 64 + gp];
#pragma unroll
      for (int j = 0; j < 4; j++)
        bf[j] = *(const bf16x8*)&Bs[(wn + j * 16 + ml) * 64 + gp];

#pragma unroll
      for (int i = 0; i < 4; i++)
#pragma unroll
        for (int j = 0; j < 4; j++)
          acc[i][j] = __builtin_amdgcn_mfma_f32_16x16x32_bf16(af[i], bf[j],
                                                              acc[i][j], 0, 0, 0);
    }
    __syncthreads();
  }

  // Epilogue: per-row partial of tanh(C + b1) . W2 ; b2 cancels in softmax.
  float b1v[4], w2v[4];
#pragma unroll
  for (int j = 0; j < 4; j++) {
    int n = n0 + wn + j * 16 + ml;
    b1v[j] = b1g[n];
    w2v[j] = W2g[n];
  }
  const int q4 = (lane >> 4) * 4;
#pragma unroll
  for (int i = 0; i < 4; i++) {
#pragma unroll
    for (int p = 0; p < 4; p++) {
      float t = 0.f;
#pragma unroll
      for (int j = 0; j < 4; j++)
        t += tanh_fast(acc[i][j][p] + b1v[j]) * w2v[j];
      t += __shfl_xor(t, 1);
      t += __shfl_xor(t, 2);
      t += __shfl_xor(t, 4);
      t += __shfl_xor(t, 8);
      if (ml == 0) atomicAdd(&scores[m0 + wm + i * 16 + q4 + p], t);
    }
  }
}

// ---------------------------------------------------------------------------
// K2: per-segment softmax + weighted sum gathered from bf16 Xb (LLC-hot).
// 192 threads x ushort4 (8B) covers a 768-elem row; 4-deep pipelined gather.
__global__ __launch_bounds__(256) void aggregate_kernel(
    const ushort* __restrict__ Xb, const float* __restrict__ scores,
    const int* __restrict__ cursor, const int* __restrict__ order,
    float4* __restrict__ out4, float* __restrict__ out_mask) {
  __shared__ float sw[CAP];
  __shared__ int   sidx[CAP];
  __shared__ float wred[4];
  const int seg = blockIdx.x;
  const int tid = threadIdx.x;
  int cnt = cursor[seg];
  if (cnt > CAP) cnt = CAP;
  if (tid == 0) out_mask[seg] = cnt > 0 ? 1.f : 0.f;
  if (cnt == 0) {
    if (tid < H_DIM / 4)
      out4[(size_t)seg * (H_DIM / 4) + tid] = make_float4(0.f, 0.f, 0.f, 0.f);
    return;
  }
  const int lane = tid & 63, wave = tid >> 6;
  float lmax = -3.4e38f;
  if (tid < cnt) {
    int idx = order[seg * CAP + tid];
    sidx[tid] = idx;
    float sc = scores[idx];
    sw[tid] = sc;
    lmax = sc;
  }
#pragma unroll
  for (int d = 1; d < 64; d <<= 1) lmax = fmaxf(lmax, __shfl_xor(lmax, d));
  if (lane == 0) wred[wave] = lmax;
  __syncthreads();
  float m = fmaxf(fmaxf(wred[0], wred[1]), fmaxf(wred[2], wred[3]));
  float lsum = 0.f;
  if (tid < cnt) {
    float e = __expf(sw[tid] - m);
    sw[tid] = e;
    lsum = e;
  }
#pragma unroll
  for (int d = 1; d < 64; d <<= 1) lsum += __shfl_xor(lsum, d);
  __syncthreads();                 // wred(max) consumed before overwrite
  if (lane == 0) wred[wave] = lsum;
  __syncthreads();
  float denom = wred[0] + wred[1] + wred[2] + wred[3];
  float inv = __builtin_amdgcn_rcpf(fmaxf(denom, 1e-20f));
  if (tid < cnt) sw[tid] *= inv;
  __syncthreads();
  if (tid < H_DIM / 4) {           // 192 lanes, 8B each
    const ushort4* base = (const ushort4*)Xb + tid;  // elem offset = tid*4
    float4 acc = make_float4(0.f, 0.f, 0.f, 0.f);
    int t = 0;
    for (; t + 4 <= cnt; t += 4) { // 4 independent loads in flight
      ushort4 u0 = base[(size_t)sidx[t]     * (H_DIM / 4)];
      ushort4 u1 = base[(size_t)sidx[t + 1] * (H_DIM / 4)];
      ushort4 u2 = base[(size_t)sidx[t + 2] * (H_DIM / 4)];
      ushort4 u3 = base[(size_t)sidx[t + 3] * (H_DIM / 4)];
      float w0 = sw[t], w1 = sw[t + 1], w2 = sw[t + 2], w3 = sw[t + 3];
      acc.x += w0 * bf2f(u0.x) + w1 * bf2f(u1.x) + w2 * bf2f(u2.x) + w3 * bf2f(u3.x);
      acc.y += w0 * bf2f(u0.y) + w1 * bf2f(u1.y) + w2 * bf2f(u2.y) + w3 * bf2f(u3.y);
      acc.z += w0 * bf2f(u0.z) + w1 * bf2f(u1.z) + w2 * bf2f(u2.z) + w3 * bf2f(u3.z);
      acc.w += w0 * bf2f(u0.w) + w1 * bf2f(u1.w) + w2 * bf2f(u2.w) + w3 * bf2f(u3.w);
    }
    for (; t < cnt; ++t) {
      ushort4 u = base[(size_t)sidx[t] * (H_DIM / 4)];
      float w = sw[t];
      acc.x += w * bf2f(u.x); acc.y += w * bf2f(u.y);
      acc.z += w * bf2f(u.z); acc.w += w * bf2f(u.w);
    }
    out4[(size_t)seg * (H_DIM / 4) + tid] = acc;
  }
}

// ---------------------------------------------------------------------------
extern "C" void kernel_launch(void* const* d_in, const int* in_sizes, int n_in,
                              void* d_out, int out_size, void* d_ws, size_t ws_size,
                              hipStream_t stream) {
  const float* X        = (const float*)d_in[0];
  const int*   line_ids = (const int*)d_in[1];
  const float* W1       = (const float*)d_in[2];
  const float* b1       = (const float*)d_in[3];
  const float* W2       = (const float*)d_in[4];
  // d_in[5] = b2: constant shift, cancels in softmax -> unused.

  char* p = (char*)d_ws;
  __hip_bfloat16* Xb  = (__hip_bfloat16*)p;  p += (size_t)M_TOK * H_DIM * 2;
  __hip_bfloat16* W1t = (__hip_bfloat16*)p;  p += 1572864;
  float* scores  = (float*)p;                p += 131072;
  int*   cursor  = (int*)p;                  p += 8192;
  int*   order   = (int*)p;                  p += (size_t)NSEG * CAP * 4;

  float* out_feats = (float*)d_out;
  float* out_mask  = out_feats + (size_t)NSEG * H_DIM;

  // zero scores + cursor (contiguous region)
  hipMemsetAsync(scores, 0, 131072 + 8192, stream);

  prep_kernel<<<896 + CONV_BLOCKS, 256, 0, stream>>>(
      W1, W1t, line_ids, cursor, order, (const float4*)X, (uint4*)Xb);
  attn_score_kernel<<<2048, 256, 0, stream>>>(Xb, W1t, b1, W2, scores);
  aggregate_kernel<<<NSEG, 256, 0, stream>>>((const ushort*)Xb, scores, cursor,
                                             order, (float4*)out_feats, out_mask);
}

// Round 8
// 247.631 us; speedup vs baseline: 1.0959x; 1.0184x over previous
//
#include <hip/hip_runtime.h>
#include <hip/hip_bf16.h>
#include <string.h>

// Problem constants (B=8, S=4096, H=768, L=256, ATT_HID=1024)
#define M_TOK 32768   // B*S
#define H_DIM 768
#define AH    1024
#define NSEG  2048    // B*L
#define LCAP  192     // aggregate LDS token-list capacity (binomial mean 16, max ~40)
#define CONV_BLOCKS 12288  // M_TOK*H_DIM / 8 elems-per-thread / 256 threads

typedef __attribute__((ext_vector_type(8))) __bf16 bf16x8;
typedef __attribute__((ext_vector_type(4))) float f32x4;

// Fast tanh: 1 - 2/(exp(2x)+1). Saturates correctly; ~1e-5 rel err.
__device__ __forceinline__ float tanh_fast(float x) {
  float e = __expf(2.0f * x);
  return 1.0f - 2.0f * __builtin_amdgcn_rcpf(e + 1.0f);
}

__device__ __forceinline__ float bf2f(unsigned short u) {
  unsigned int v = (unsigned int)u << 16;
  float f;
  memcpy(&f, &v, 4);
  return f;
}

// ---------------------------------------------------------------------------
// K0: prep, two block ranges:
//   [0,768)          : transpose+convert W1 fp32 [768,1024] -> W1t bf16 [1024,768]
//   [768,768+12288)  : convert X fp32 -> Xb bf16, 8 elems/thread
__global__ __launch_bounds__(256) void prep_kernel(
    const float* __restrict__ W1, __hip_bfloat16* __restrict__ W1t,
    const float4* __restrict__ X4, uint4* __restrict__ Xb4) {
  __shared__ float tile[32][33];
  if (blockIdx.x < 768) {
    int nt = blockIdx.x & 31, ktile = blockIdx.x >> 5;
    int n0 = nt * 32, k0 = ktile * 32;
    int tx = threadIdx.x & 31, ty = threadIdx.x >> 5;  // ty 0..7
    for (int r = ty; r < 32; r += 8)
      tile[r][tx] = W1[(size_t)(k0 + r) * AH + n0 + tx];
    __syncthreads();
    for (int r = ty; r < 32; r += 8)
      W1t[(size_t)(n0 + r) * H_DIM + k0 + tx] = __float2bfloat16(tile[tx][r]);
  } else {
    int i = (blockIdx.x - 768) * 256 + threadIdx.x;  // 8 elems per thread
    float4 v0 = X4[i * 2];
    float4 v1 = X4[i * 2 + 1];
    __hip_bfloat16 h[8] = {
        __float2bfloat16(v0.x), __float2bfloat16(v0.y),
        __float2bfloat16(v0.z), __float2bfloat16(v0.w),
        __float2bfloat16(v1.x), __float2bfloat16(v1.y),
        __float2bfloat16(v1.z), __float2bfloat16(v1.w)};
    uint4 p;
    memcpy(&p, h, 16);
    Xb4[i] = p;
  }
}

// ---------------------------------------------------------------------------
// K1: fused partial scores = tanh(Xb @ W1t^T + b1) . W2 per n-tile.
// 128x128 MFMA tile, BK=64, global_load_lds width-16, XCD swizzle, XOR bank
// swizzle (granule g of row r at physical g^(r&7); zero LDS conflicts).
// No atomics / no pre-zero: each n-tile writes scores2[m*8 + ntile]; the
// wave-pair (wn=0 / wn=64) is reduced via a 512B LDS buffer (reuses As).
__global__ __launch_bounds__(256) void attn_score_kernel(
    const __hip_bfloat16* __restrict__ Xbg,
    const __hip_bfloat16* __restrict__ W1tg, const float* __restrict__ b1g,
    const float* __restrict__ W2g, float* __restrict__ scores2) {
  __shared__ __align__(16) __bf16 As[128 * 64];   // 16 KB
  __shared__ __align__(16) __bf16 Bs[128 * 64];   // 16 KB

  const int tid = threadIdx.x;
  const int bid = blockIdx.x;
  const int xcd = bid & 7;                      // lands on XCD bid%8
  const int s   = bid >> 3;                     // 0..255 sequence on that XCD
  const int m0  = (xcd * 32 + (s >> 3)) * 128;  // 32 m-tiles per XCD
  const int nt  = s & 7;                        // n-tile index 0..7
  const int n0  = nt * 128;
  const int lane = tid & 63;
  const int wave = tid >> 6;
  const int wm   = (wave >> 1) * 64;
  const int wn   = (wave & 1) * 64;
  const int ml   = lane & 15;
  const int gsw  = lane & 7;                    // == row&7 for fragment rows

  const __bf16* Xb = (const __bf16*)Xbg;
  const __bf16* W  = (const __bf16*)W1tg;

  // Staging: thread t covers row (p*32 + t>>3), swizzled granule (t&7)^(row&7).
  const int srow = tid >> 3;                       // 0..31
  const int scol = ((tid & 7) ^ (srow & 7)) * 8;   // swizzled source column

  f32x4 acc[4][4];
#pragma unroll
  for (int i = 0; i < 4; i++)
#pragma unroll
    for (int j = 0; j < 4; j++) acc[i][j] = (f32x4)0.f;

  for (int kt = 0; kt < H_DIM; kt += 64) {
#pragma unroll
    for (int p = 0; p < 4; ++p) {
      const __bf16* ga = Xb + (size_t)(m0 + p * 32 + srow) * H_DIM + kt + scol;
      __builtin_amdgcn_global_load_lds(
          (const __attribute__((address_space(1))) void*)ga,
          (__attribute__((address_space(3))) void*)&As[p * 2048 + tid * 8],
          16, 0, 0);
      const __bf16* gb = W + (size_t)(n0 + p * 32 + srow) * H_DIM + kt + scol;
      __builtin_amdgcn_global_load_lds(
          (const __attribute__((address_space(1))) void*)gb,
          (__attribute__((address_space(3))) void*)&Bs[p * 2048 + tid * 8],
          16, 0, 0);
    }
    __syncthreads();

#pragma unroll
    for (int c = 0; c < 2; ++c) {
      const int gq = c * 4 + (lane >> 4);          // logical granule 0..7
      const int gp = (gq ^ gsw) * 8;               // physical (swizzled)
      bf16x8 af[4], bf[4];
#pragma unroll
      for (int i = 0; i < 4; i++)
        af[i] = *(const bf16x8*)&As[(wm + i * 16 + ml) * 64 + gp];
#pragma unroll
      for (int j = 0; j < 4; j++)
        bf[j] = *(const bf16x8*)&Bs[(wn + j * 16 + ml) * 64 + gp];

#pragma unroll
      for (int i = 0; i < 4; i++)
#pragma unroll
        for (int j = 0; j < 4; j++)
          acc[i][j] = __builtin_amdgcn_mfma_f32_16x16x32_bf16(af[i], bf[j],
                                                              acc[i][j], 0, 0, 0);
    }
    __syncthreads();
  }

  // Epilogue: per-row partial of tanh(C + b1) . W2 ; b2 cancels in softmax.
  float b1v[4], w2v[4];
#pragma unroll
  for (int j = 0; j < 4; j++) {
    int n = n0 + wn + j * 16 + ml;
    b1v[j] = b1g[n];
    w2v[j] = W2g[n];
  }
  const int q4 = (lane >> 4) * 4;
  float tval[4][4];
#pragma unroll
  for (int i = 0; i < 4; i++) {
#pragma unroll
    for (int p = 0; p < 4; p++) {
      float t = 0.f;
#pragma unroll
      for (int j = 0; j < 4; j++)
        t += tanh_fast(acc[i][j][p] + b1v[j]) * w2v[j];
      t += __shfl_xor(t, 1);
      t += __shfl_xor(t, 2);
      t += __shfl_xor(t, 4);
      t += __shfl_xor(t, 8);
      tval[i][p] = t;   // valid on ml==0 lanes
    }
  }
  // Reduce the wn=0 / wn=64 wave pair via LDS (As is free after the K-loop;
  // the K-loop's trailing __syncthreads() ordered all reads before this).
  float* redbuf = (float*)As;   // 128 floats
  if ((wave & 1) && ml == 0) {
#pragma unroll
    for (int i = 0; i < 4; i++)
#pragma unroll
      for (int p = 0; p < 4; p++)
        redbuf[wm + i * 16 + q4 + p] = tval[i][p];
  }
  __syncthreads();
  if (!(wave & 1) && ml == 0) {
#pragma unroll
    for (int i = 0; i < 4; i++)
#pragma unroll
      for (int p = 0; p < 4; p++) {
        int row = wm + i * 16 + q4 + p;
        scores2[(size_t)(m0 + row) * 8 + nt] = tval[i][p] + redbuf[row];
      }
  }
}

// ---------------------------------------------------------------------------
// K2: self-sufficient aggregate: ballot-compacts this segment's token list
// straight from line_ids (16 KB per batch, L2-hot across its 256 blocks),
// sums the 8 score partials, softmax, bf16 gather weighted sum.
// No cursor/order/memset dependencies.
__global__ __launch_bounds__(256) void aggregate_kernel(
    const ushort* __restrict__ Xb, const float* __restrict__ scores2,
    const int* __restrict__ line_ids, float4* __restrict__ out4,
    float* __restrict__ out_mask) {
  __shared__ int   slist[LCAP];
  __shared__ float sw[LCAP];
  __shared__ int   wvc[4];
  __shared__ float wred[4];
  const int seg = blockIdx.x;
  const int b = seg >> 8, lid = seg & 255;
  const int tid = threadIdx.x, lane = tid & 63, wave = tid >> 6;
  const int base = b * 4096;

  int ids[16];
#pragma unroll
  for (int c = 0; c < 16; ++c) ids[c] = line_ids[base + c * 256 + tid];

  int total = 0;
#pragma unroll
  for (int c = 0; c < 16; ++c) {
    bool match = (ids[c] == lid);
    unsigned long long mask = __ballot(match);
    if (lane == 0) wvc[wave] = __popcll(mask);
    __syncthreads();
    int off = total;
    for (int w = 0; w < wave; ++w) off += wvc[w];
    if (match) {
      int pos = off + __popcll(mask & ((1ull << lane) - 1ull));
      if (pos < LCAP) slist[pos] = base + c * 256 + tid;
    }
    total += wvc[0] + wvc[1] + wvc[2] + wvc[3];
    __syncthreads();
  }
  int cnt = total > LCAP ? LCAP : total;
  if (tid == 0) out_mask[seg] = cnt > 0 ? 1.f : 0.f;
  if (cnt == 0) {
    if (tid < H_DIM / 4)
      out4[(size_t)seg * (H_DIM / 4) + tid] = make_float4(0.f, 0.f, 0.f, 0.f);
    return;
  }
  float lmax = -3.4e38f;
  if (tid < cnt) {
    const float4* sp = (const float4*)(scores2 + (size_t)slist[tid] * 8);
    float4 a = sp[0], c4 = sp[1];
    float sc = ((a.x + a.y) + (a.z + a.w)) + ((c4.x + c4.y) + (c4.z + c4.w));
    sw[tid] = sc;
    lmax = sc;
  }
#pragma unroll
  for (int d = 1; d < 64; d <<= 1) lmax = fmaxf(lmax, __shfl_xor(lmax, d));
  if (lane == 0) wred[wave] = lmax;
  __syncthreads();
  float m = fmaxf(fmaxf(wred[0], wred[1]), fmaxf(wred[2], wred[3]));
  float lsum = 0.f;
  if (tid < cnt) {
    float e = __expf(sw[tid] - m);
    sw[tid] = e;
    lsum = e;
  }
#pragma unroll
  for (int d = 1; d < 64; d <<= 1) lsum += __shfl_xor(lsum, d);
  __syncthreads();                 // wred(max) consumed before overwrite
  if (lane == 0) wred[wave] = lsum;
  __syncthreads();
  float denom = wred[0] + wred[1] + wred[2] + wred[3];
  float inv = __builtin_amdgcn_rcpf(fmaxf(denom, 1e-20f));
  if (tid < cnt) sw[tid] *= inv;
  __syncthreads();
  if (tid < H_DIM / 4) {           // 192 lanes, 8B each, coalesced per row
    const ushort4* xb = (const ushort4*)Xb + tid;  // elem offset = tid*4
    float4 acc = make_float4(0.f, 0.f, 0.f, 0.f);
    int t = 0;
    for (; t + 4 <= cnt; t += 4) { // 4 independent loads in flight
      ushort4 u0 = xb[(size_t)slist[t]     * (H_DIM / 4)];
      ushort4 u1 = xb[(size_t)slist[t + 1] * (H_DIM / 4)];
      ushort4 u2 = xb[(size_t)slist[t + 2] * (H_DIM / 4)];
      ushort4 u3 = xb[(size_t)slist[t + 3] * (H_DIM / 4)];
      float w0 = sw[t], w1 = sw[t + 1], w2 = sw[t + 2], w3 = sw[t + 3];
      acc.x += w0 * bf2f(u0.x) + w1 * bf2f(u1.x) + w2 * bf2f(u2.x) + w3 * bf2f(u3.x);
      acc.y += w0 * bf2f(u0.y) + w1 * bf2f(u1.y) + w2 * bf2f(u2.y) + w3 * bf2f(u3.y);
      acc.z += w0 * bf2f(u0.z) + w1 * bf2f(u1.z) + w2 * bf2f(u2.z) + w3 * bf2f(u3.z);
      acc.w += w0 * bf2f(u0.w) + w1 * bf2f(u1.w) + w2 * bf2f(u2.w) + w3 * bf2f(u3.w);
    }
    for (; t < cnt; ++t) {
      ushort4 u = xb[(size_t)slist[t] * (H_DIM / 4)];
      float w = sw[t];
      acc.x += w * bf2f(u.x); acc.y += w * bf2f(u.y);
      acc.z += w * bf2f(u.z); acc.w += w * bf2f(u.w);
    }
    out4[(size_t)seg * (H_DIM / 4) + tid] = acc;
  }
}

// ---------------------------------------------------------------------------
extern "C" void kernel_launch(void* const* d_in, const int* in_sizes, int n_in,
                              void* d_out, int out_size, void* d_ws, size_t ws_size,
                              hipStream_t stream) {
  const float* X        = (const float*)d_in[0];
  const int*   line_ids = (const int*)d_in[1];
  const float* W1       = (const float*)d_in[2];
  const float* b1       = (const float*)d_in[3];
  const float* W2       = (const float*)d_in[4];
  // d_in[5] = b2: constant shift, cancels in softmax -> unused.

  char* p = (char*)d_ws;
  __hip_bfloat16* Xb      = (__hip_bfloat16*)p;  p += (size_t)M_TOK * H_DIM * 2;
  __hip_bfloat16* W1t     = (__hip_bfloat16*)p;  p += 1572864;
  float*          scores2 = (float*)p;           p += (size_t)M_TOK * 8 * 4;

  float* out_feats = (float*)d_out;
  float* out_mask  = out_feats + (size_t)NSEG * H_DIM;

  prep_kernel<<<768 + CONV_BLOCKS, 256, 0, stream>>>(
      W1, W1t, (const float4*)X, (uint4*)Xb);
  attn_score_kernel<<<2048, 256, 0, stream>>>(Xb, W1t, b1, W2, scores2);
  aggregate_kernel<<<NSEG, 256, 0, stream>>>((const ushort*)Xb, scores2,
                                             line_ids, (float4*)out_feats,
                                             out_mask);
}